// Round 10
// baseline (258.647 us; speedup 1.0000x reference)
//
#include <hip/hip_runtime.h>
#include <cmath>

// FusionLoss = ms_ssim(fus,ir)+ms_ssim(fus,vi) + l1(max(map_ir,map_vi),fus)
//            + 10*mean(|max(|lap ir|,|lap vi|) - |lap fus||)
// Inputs: im_fus, im_ir, im_vi, map_ir, map_vi  each [32,1,512,512] fp32.
//
// d_ws layout (floats): [0..1024)    ssim partials  (1024 ssim blocks)
//                       [1024..3072) l1 partials    (2048 lapl1 blocks)
//                       [3072..5120) grad partials  (2048 lapl1 blocks)
//
// Journal: r2 atomics->partials (306->126us). r5/r6/r8 FAILED (spill: VGPR
// cap / fused union / float4-srow quads). r7 768-block one-round grid,
// scalar srow: 80.8us. r9 packed-f32 pairs {hf,hi}{hff,hii}{hfi,hfv}{hv,hvv}
// via v_pk_fma_f32 + {F,I} b64 LDS: 72.9us, VGPR 80, VALUBusy 64%, occ 24%.
// r9 model: VALU-busy 47us, DS 34us, ~26us un-hidden LDS latency (3 w/SIMD).
// r10 single change: 4 blocks/CU (launch_bounds(256,4), 1024 blocks of
// 32-row strips, all resident one round) -> 4 waves/SIMD latency hiding.
// GUARDS: WRITE_SIZE<=50KB, VGPR<=128 else spill -> revert.

typedef float f32x2 __attribute__((ext_vector_type(2)));

struct GaussW { float w[11]; };

#define SSIM_C1 1.0e-4f
#define SSIM_C2 9.0e-4f

// ---------------- Kernel A: fused double SSIM (separable 11x11 gaussian) ----
// Grid: (2 col blocks of 256, 16 row strips of 32, 32 batch) = 1024 blocks
// = 4 blocks/CU x 256 CU resident in ONE round (no tail).
// Block = 4 independent waves; wave wv owns 64 cols; wave-private LDS rows.
// No __syncthreads in the main loop (in-order DS pipe within a wave;
// wave_barrier() fences compiler reordering, zero-cost).
// Vertical gaussian via an 11-slot register ring of f32x2 pairs; slot
// (o mod 11) is OVERWRITTEN by the k=0 term when output row o begins
// (wipes phantom o<0 garbage from the 10 warm-up rows).
__global__ __launch_bounds__(256, 4)
void ssim_kernel(const float* __restrict__ fus, const float* __restrict__ irp,
                 const float* __restrict__ vip, float* __restrict__ part,
                 GaussW gw)
{
    const int b    = blockIdx.z;
    const int r0   = blockIdx.y * 32;
    const int tid  = threadIdx.x;
    const int wv   = tid >> 6;          // wave 0..3
    const int lane = tid & 63;
    const int c0   = blockIdx.x * 256 + wv * 64;   // wave's column base
    const int out_rows = min(32, 502 - r0);        // last strip: 22
    const int in_rows  = out_rows + 10;            // <= 42

    const size_t ib = (size_t)b * 512 * 512;
    const float* __restrict__ Fp = fus + ib;
    const float* __restrict__ Ip = irp + ib;
    const float* __restrict__ Vp = vip + ib;

    __shared__ f32x2 srow_fi[4][80];    // wave-private {F,I} pairs
    __shared__ float srow_v [4][80];    // wave-private V

    float w6[6];                        // gaussian symmetric: w[k]=w[10-k]
#pragma unroll
    for (int k = 0; k < 6; ++k) w6[k] = gw.w[k];

    // register ring: 11 rows x 4 f32x2 pairs:
    //   [0]={hf,hi} [1]={hff,hii} [2]={hfi,hfv} [3]={hv,hvv}
    f32x2 acc[11][4];
#pragma unroll
    for (int s = 0; s < 11; ++s)
#pragma unroll
        for (int q = 0; q < 4; ++q) acc[s][q] = (f32x2)(0.f);

    float lssim = 0.f;
    const int  col      = c0 + lane;
    const bool col_ok   = col <= 501;             // valid output column
    const bool extra    = lane < 10;              // loads the 10-col halo
    const int  col2     = c0 + 64 + lane;
    const bool extra_ok = extra && (col2 < 512);

    // prefetch input row 0
    float rf, rg, rv, rf2 = 0.f, rg2 = 0.f, rv2 = 0.f;
    {
        const size_t base = (size_t)r0 * 512 + col;
        rf = Fp[base]; rg = Ip[base]; rv = Vp[base];
        if (extra_ok) {
            const size_t b2 = (size_t)r0 * 512 + col2;
            rf2 = Fp[b2]; rg2 = Ip[b2]; rv2 = Vp[b2];
        }
    }

#pragma unroll 1
    for (int rb = 0; rb < 44; rb += 11) {
#pragma unroll
        for (int p = 0; p < 11; ++p) {
            const int r = rb + p;                 // input row within strip
            if (r < in_rows) {                    // wave-uniform guard
                // stage row r (ds_write_b64 pair + b32 V, + halo)
                srow_fi[wv][lane] = (f32x2){rf, rg};
                srow_v [wv][lane] = rv;
                if (extra) {
                    srow_fi[wv][64 + lane] = (f32x2){rf2, rg2};
                    srow_v [wv][64 + lane] = rv2;
                }
                __builtin_amdgcn_wave_barrier();  // fence write->read order

                // prefetch row r+1 (hides under compute below)
                if (r + 1 < in_rows) {
                    const size_t base = (size_t)(r0 + r + 1) * 512 + col;
                    rf = Fp[base]; rg = Ip[base]; rv = Vp[base];
                    if (extra_ok) {
                        const size_t b2 = (size_t)(r0 + r + 1) * 512 + col2;
                        rf2 = Fp[b2]; rg2 = Ip[b2]; rv2 = Vp[b2];
                    }
                }

                // horizontal gaussian sums, packed-f32 where pairable
                f32x2 hfhi = (f32x2)(0.f);   // {Σw·F, Σw·I}
                f32x2 hffii = (f32x2)(0.f);  // {Σw·F², Σw·I²}
                f32x2 hfifv = (f32x2)(0.f);  // {Σw·F·I, Σw·F·V}
                f32x2 hvvv = (f32x2)(0.f);   // {Σw·V, Σw·V²}
#pragma unroll
                for (int k = 0; k < 11; ++k) {
                    const float t = w6[k < 6 ? k : 10 - k];
                    const f32x2 fi = srow_fi[wv][lane + k];
                    const float V  = srow_v [wv][lane + k];
                    const f32x2 t2 = (f32x2){t, t};
                    const f32x2 tfi = t2 * fi;                      // pk_mul
                    hfhi  = __builtin_elementwise_fma(t2,  fi, hfhi);   // pk_fma
                    hffii = __builtin_elementwise_fma(tfi, fi, hffii);  // pk_fma
                    hfifv.x = fmaf(tfi.x, fi.y, hfifv.x);           // w·F·I
                    hfifv.y = fmaf(tfi.x, V,    hfifv.y);           // w·F·V
                    const float tV = t * V;
                    hvvv.x = fmaf(t,  V, hvvv.x);                   // w·V
                    hvvv.y = fmaf(tV, V, hvvv.y);                   // w·V²
                }
                __builtin_amdgcn_wave_barrier();  // fence read->next-write

                // vertical ring: k=0 OVERWRITES slot p, k>=1 accumulates.
                {
                    const f32x2 w02 = (f32x2){w6[0], w6[0]};
                    acc[p][0] = w02 * hfhi;
                    acc[p][1] = w02 * hffii;
                    acc[p][2] = w02 * hfifv;
                    acc[p][3] = w02 * hvvv;
                }
#pragma unroll
                for (int k = 1; k < 11; ++k) {
                    const int s = (p - k + 11) % 11;   // compile-time
                    const float t = w6[k < 6 ? k : 10 - k];
                    const f32x2 t2 = (f32x2){t, t};
                    acc[s][0] = __builtin_elementwise_fma(t2, hfhi,  acc[s][0]);
                    acc[s][1] = __builtin_elementwise_fma(t2, hffii, acc[s][1]);
                    acc[s][2] = __builtin_elementwise_fma(t2, hfifv, acc[s][2]);
                    acc[s][3] = __builtin_elementwise_fma(t2, hvvv,  acc[s][3]);
                }
                // finalize output row r-10 (its slot just got its k=10 term)
                if (r >= 10) {
                    const int s = (p + 1) % 11;        // compile-time
                    const float mu1 = acc[s][0].x, mu2 = acc[s][0].y, mu3 = acc[s][3].x;
                    const float eff = acc[s][1].x, eii = acc[s][1].y, evv = acc[s][3].y;
                    const float efi = acc[s][2].x, efv = acc[s][2].y;
                    const float mu1sq = mu1*mu1, mu2sq = mu2*mu2, mu3sq = mu3*mu3;
                    const float mu12 = mu1*mu2, mu13 = mu1*mu3;
                    const float sf  = eff - mu1sq;
                    const float si  = eii - mu2sq;
                    const float sv  = evv - mu3sq;
                    const float s12 = efi - mu12;
                    const float s13 = efv - mu13;
                    const float n1 = (2.f*mu12 + SSIM_C1) * (2.f*s12 + SSIM_C2);
                    const float d1 = (mu1sq + mu2sq + SSIM_C1) * (sf + si + SSIM_C2);
                    const float n2 = (2.f*mu13 + SSIM_C1) * (2.f*s13 + SSIM_C2);
                    const float d2 = (mu1sq + mu3sq + SSIM_C1) * (sf + sv + SSIM_C2);
                    // v_rcp_f32 (~2^-22 rel err) vs 6.6e-2 tolerance: free
                    const float q1 = __builtin_amdgcn_rcpf(d1);
                    const float q2 = __builtin_amdgcn_rcpf(d2);
                    if (col_ok) lssim += fmaf(n1, q1, n2 * q2);
                }
            }
        }
    }

    // cross-wave block reduction -> one partial write (no atomic)
#pragma unroll
    for (int off = 32; off > 0; off >>= 1)
        lssim += __shfl_down(lssim, off);
    __shared__ float red[4];
    if (lane == 0) red[wv] = lssim;
    __syncthreads();
    if (tid == 0) {
        const int blk = blockIdx.x + 2 * (blockIdx.y + 16 * blockIdx.z); // 0..1023
        part[blk] = red[0] + red[1] + red[2] + red[3];
    }
}

// ---------------- Kernel B: L1 + laplacian grad loss ------------------------
__device__ inline float4 lap3x3(const float* __restrict__ rm,
                                const float* __restrict__ rc,
                                const float* __restrict__ rp,
                                int x0, int xl, int xr, float4& center)
{
    float4 a = *(const float4*)(rm + x0);
    float4 b = *(const float4*)(rc + x0);
    float4 c = *(const float4*)(rp + x0);
    const float aL = rm[xl], bL = rc[xl], cL = rp[xl];
    const float aR = rm[xr], bR = rc[xr], cR = rp[xr];
    const float s0 = aL + bL + cL;
    const float s1 = a.x + b.x + c.x;
    const float s2 = a.y + b.y + c.y;
    const float s3 = a.z + b.z + c.z;
    const float s4 = a.w + b.w + c.w;
    const float s5 = aR + bR + cR;
    center = b;
    float4 l;
    l.x = (s0 + s1 + s2 - 9.f*b.x) * 0.0625f;
    l.y = (s1 + s2 + s3 - 9.f*b.y) * 0.0625f;
    l.z = (s2 + s3 + s4 - 9.f*b.z) * 0.0625f;
    l.w = (s3 + s4 + s5 - 9.f*b.w) * 0.0625f;
    return l;
}

// Grid: dim3(64, 32) = 2048 blocks; each block covers 8 rows of one batch
// image (4 iterations x 2 rows). Partial sums to d_ws, no atomics.
__global__ __launch_bounds__(256, 4)
void lapl1_kernel(const float* __restrict__ fus, const float* __restrict__ irp,
                  const float* __restrict__ vip, const float* __restrict__ mir,
                  const float* __restrict__ mvi,
                  float* __restrict__ part_l1, float* __restrict__ part_gr)
{
    const int b   = blockIdx.y;
    const int tid = threadIdx.x;
    const int xq  = tid & 127;
    const int x0  = xq * 4;
    const size_t ib = (size_t)b * 512 * 512;

    const int xl = (x0 == 0)        ? 1   : x0 - 1;   // reflect padding (x)
    const int xr = (x0 + 4 == 512)  ? 510 : x0 + 4;

    const float* Fb = fus + ib;
    const float* Ib = irp + ib;
    const float* Vb = vip + ib;

    float l1s = 0.f, grs = 0.f;

#pragma unroll
    for (int it = 0; it < 4; ++it) {
        const int y  = blockIdx.x * 8 + it * 2 + (tid >> 7);
        const int ym = (y == 0)   ? 1   : y - 1;       // reflect padding (y)
        const int yp = (y == 511) ? 510 : y + 1;

        float4 cf, ci, cv;
        const float4 lf = lap3x3(Fb + (size_t)ym*512, Fb + (size_t)y*512, Fb + (size_t)yp*512, x0, xl, xr, cf);
        const float4 li = lap3x3(Ib + (size_t)ym*512, Ib + (size_t)y*512, Ib + (size_t)yp*512, x0, xl, xr, ci);
        const float4 lv = lap3x3(Vb + (size_t)ym*512, Vb + (size_t)y*512, Vb + (size_t)yp*512, x0, xl, xr, cv);

        const float4 m1 = *(const float4*)(mir + ib + (size_t)y*512 + x0);
        const float4 m2 = *(const float4*)(mvi + ib + (size_t)y*512 + x0);

        l1s += fabsf(fmaxf(m1.x, m2.x) - cf.x) + fabsf(fmaxf(m1.y, m2.y) - cf.y)
             + fabsf(fmaxf(m1.z, m2.z) - cf.z) + fabsf(fmaxf(m1.w, m2.w) - cf.w);

        grs += fabsf(fmaxf(fabsf(li.x), fabsf(lv.x)) - fabsf(lf.x))
             + fabsf(fmaxf(fabsf(li.y), fabsf(lv.y)) - fabsf(lf.y))
             + fabsf(fmaxf(fabsf(li.z), fabsf(lv.z)) - fabsf(lf.z))
             + fabsf(fmaxf(fabsf(li.w), fabsf(lv.w)) - fabsf(lf.w));
    }

#pragma unroll
    for (int off = 32; off > 0; off >>= 1) {
        l1s += __shfl_down(l1s, off);
        grs += __shfl_down(grs, off);
    }
    __shared__ float red[8];
    if ((tid & 63) == 0) { red[tid >> 6] = l1s; red[4 + (tid >> 6)] = grs; }
    __syncthreads();
    if (tid == 0) {
        const int blk = blockIdx.x + 64 * blockIdx.y;  // 0..2047
        part_l1[blk] = red[0] + red[1] + red[2] + red[3];
        part_gr[blk] = red[4] + red[5] + red[6] + red[7];
    }
}

// ---------------- final combine: reduce all partials ------------------------
__global__ void final_kernel(const float* __restrict__ ws, float* __restrict__ out)
{
    const int tid = threadIdx.x;
    float s0 = 0.f, s1 = 0.f, s2 = 0.f;
#pragma unroll
    for (int i = tid; i < 1024; i += 256) s0 += ws[i];
#pragma unroll
    for (int i = tid; i < 2048; i += 256) {
        s1 += ws[1024 + i];
        s2 += ws[3072 + i];
    }
#pragma unroll
    for (int off = 32; off > 0; off >>= 1) {
        s0 += __shfl_down(s0, off);
        s1 += __shfl_down(s1, off);
        s2 += __shfl_down(s2, off);
    }
    __shared__ float red[12];
    if ((tid & 63) == 0) {
        red[tid >> 6] = s0; red[4 + (tid >> 6)] = s1; red[8 + (tid >> 6)] = s2;
    }
    __syncthreads();
    if (tid == 0) {
        const float ssim_sum = red[0] + red[1] + red[2] + red[3];
        const float l1_sum   = red[4] + red[5] + red[6] + red[7];
        const float gr_sum   = red[8] + red[9] + red[10] + red[11];
        const float ms = 2.f - ssim_sum / 8064128.f;   // 32*502*502
        const float l1 = l1_sum / 8388608.f;           // 32*512*512
        const float gr = gr_sum / 8388608.f;
        out[0] = ms + l1 + 10.f * gr;
    }
}

extern "C" void kernel_launch(void* const* d_in, const int* in_sizes, int n_in,
                              void* d_out, int out_size, void* d_ws, size_t ws_size,
                              hipStream_t stream)
{
    const float* fus = (const float*)d_in[0];
    const float* irp = (const float*)d_in[1];
    const float* vip = (const float*)d_in[2];
    const float* mir = (const float*)d_in[3];
    const float* mvi = (const float*)d_in[4];
    float* out = (float*)d_out;
    float* ws  = (float*)d_ws;

    // gaussian window (matches np: f64 normalize, cast to f32)
    GaussW gw;
    double g[11], s = 0.0;
    for (int i = 0; i < 11; ++i) {
        const double d = (double)i - 5.0;
        g[i] = std::exp(-(d * d) / (2.0 * 1.5 * 1.5));
        s += g[i];
    }
    for (int i = 0; i < 11; ++i) gw.w[i] = (float)(g[i] / s);

    ssim_kernel<<<dim3(2, 16, 32), 256, 0, stream>>>(fus, irp, vip, ws, gw);
    lapl1_kernel<<<dim3(64, 32), 256, 0, stream>>>(fus, irp, vip, mir, mvi,
                                                   ws + 1024, ws + 3072);
    final_kernel<<<1, 256, 0, stream>>>(ws, out);
}

// Round 11
// 112.641 us; speedup vs baseline: 2.2962x; 2.2962x over previous
//
#include <hip/hip_runtime.h>
#include <cmath>

// FusionLoss = ms_ssim(fus,ir)+ms_ssim(fus,vi) + l1(max(map_ir,map_vi),fus)
//            + 10*mean(|max(|lap ir|,|lap vi|) - |lap fus||)
// Inputs: im_fus, im_ir, im_vi, map_ir, map_vi  each [32,1,512,512] fp32.
//
// d_ws layout (floats): [0..768)     ssim partials  (768 ssim roles)
//                       [768..2816)  l1 partials    (2048 lapl1 roles)
//                       [2816..4864) grad partials  (2048 lapl1 roles)
//
// Journal: r2 atomics->partials. r5/r8/r10 FAILED spills (launch_bounds(64,4)
// VGPR=64 cap; float4-srow b128 quads; launch_bounds(256,4) caps VGPR at
// 512/(2N)=64). r7 scalar srow 80.8us. r9 packed-f32 pk_fma + {F,I} b64 LDS:
// ssim 72.9us @ VGPR 80, total 110.9us. r6 fusion "failure" was confounded by
// float4 srow (r8 proved it spills alone). r11: clean fusion test — r9's exact
// ssim path + r7's exact lapl1 path, roles INTERLEAVED (bid%11<3 -> ssim) so
// each CU hosts ~2 ssim + ~4 lapl1 blocks (VGPR 84 allows ~6 blocks/CU);
// lapl1's HBM streaming (34us, pure memory) hides under ssim's VALU time.
// GUARDS: VGPR<=96, WRITE_SIZE<=100KB else union spilled -> revert to r9.

typedef float f32x2 __attribute__((ext_vector_type(2)));

struct GaussW { float w[11]; };

#define SSIM_C1 1.0e-4f
#define SSIM_C2 9.0e-4f

__global__ __launch_bounds__(256, 3)
void fused_kernel(const float* __restrict__ fus, const float* __restrict__ irp,
                  const float* __restrict__ vip, const float* __restrict__ mir,
                  const float* __restrict__ mvi, float* __restrict__ ws,
                  GaussW gw)
{
    const int tid = threadIdx.x;
    const int g   = blockIdx.x / 11;    // group 0..255
    const int m   = blockIdx.x % 11;    // role within group

    // LDS (both paths' arrays statically allocated; ~4KB total)
    __shared__ f32x2 srow_fi[4][80];
    __shared__ float srow_v [4][80];
    __shared__ float red[8];

    if (m < 3) {
        // ================= SSIM role: sidx in [0,768) =================
        // (2 col blocks of 256, 12 row strips of 42, 32 batch)
        const int sidx = g * 3 + m;
        const int cs   = sidx & 1;
        const int rs   = (sidx >> 1) % 12;
        const int b    = sidx / 24;
        const int wv   = tid >> 6;
        const int lane = tid & 63;
        const int r0   = rs * 42;
        const int c0   = cs * 256 + wv * 64;
        const int out_rows = min(42, 502 - r0);   // last strip: 40
        const int in_rows  = out_rows + 10;       // <= 52

        const size_t ib = (size_t)b * 512 * 512;
        const float* __restrict__ Fp = fus + ib;
        const float* __restrict__ Ip = irp + ib;
        const float* __restrict__ Vp = vip + ib;

        float w6[6];                    // gaussian symmetric: w[k]=w[10-k]
#pragma unroll
        for (int k = 0; k < 6; ++k) w6[k] = gw.w[k];

        // register ring: 11 rows x 4 f32x2 pairs:
        //   [0]={hf,hi} [1]={hff,hii} [2]={hfi,hfv} [3]={hv,hvv}
        f32x2 acc[11][4];
#pragma unroll
        for (int s = 0; s < 11; ++s)
#pragma unroll
            for (int q = 0; q < 4; ++q) acc[s][q] = (f32x2)(0.f);

        float lssim = 0.f;
        const int  col      = c0 + lane;
        const bool col_ok   = col <= 501;
        const bool extra    = lane < 10;
        const int  col2     = c0 + 64 + lane;
        const bool extra_ok = extra && (col2 < 512);

        // prefetch input row 0
        float rf, rg, rv, rf2 = 0.f, rg2 = 0.f, rv2 = 0.f;
        {
            const size_t base = (size_t)r0 * 512 + col;
            rf = Fp[base]; rg = Ip[base]; rv = Vp[base];
            if (extra_ok) {
                const size_t b2 = (size_t)r0 * 512 + col2;
                rf2 = Fp[b2]; rg2 = Ip[b2]; rv2 = Vp[b2];
            }
        }

#pragma unroll 1
        for (int rb = 0; rb < 55; rb += 11) {
#pragma unroll
            for (int p = 0; p < 11; ++p) {
                const int r = rb + p;             // input row within strip
                if (r < in_rows) {                // wave-uniform guard
                    // stage row r (ds_write_b64 pair + b32 V, + halo)
                    srow_fi[wv][lane] = (f32x2){rf, rg};
                    srow_v [wv][lane] = rv;
                    if (extra) {
                        srow_fi[wv][64 + lane] = (f32x2){rf2, rg2};
                        srow_v [wv][64 + lane] = rv2;
                    }
                    __builtin_amdgcn_wave_barrier();  // write->read order

                    // prefetch row r+1 (hides under compute below)
                    if (r + 1 < in_rows) {
                        const size_t base = (size_t)(r0 + r + 1) * 512 + col;
                        rf = Fp[base]; rg = Ip[base]; rv = Vp[base];
                        if (extra_ok) {
                            const size_t b2 = (size_t)(r0 + r + 1) * 512 + col2;
                            rf2 = Fp[b2]; rg2 = Ip[b2]; rv2 = Vp[b2];
                        }
                    }

                    // horizontal gaussian sums, packed-f32 where pairable
                    f32x2 hfhi = (f32x2)(0.f);   // {Σw·F, Σw·I}
                    f32x2 hffii = (f32x2)(0.f);  // {Σw·F², Σw·I²}
                    f32x2 hfifv = (f32x2)(0.f);  // {Σw·F·I, Σw·F·V}
                    f32x2 hvvv = (f32x2)(0.f);   // {Σw·V, Σw·V²}
#pragma unroll
                    for (int k = 0; k < 11; ++k) {
                        const float t = w6[k < 6 ? k : 10 - k];
                        const f32x2 fi = srow_fi[wv][lane + k];
                        const float V  = srow_v [wv][lane + k];
                        const f32x2 t2 = (f32x2){t, t};
                        const f32x2 tfi = t2 * fi;                      // pk_mul
                        hfhi  = __builtin_elementwise_fma(t2,  fi, hfhi);   // pk_fma
                        hffii = __builtin_elementwise_fma(tfi, fi, hffii);  // pk_fma
                        hfifv.x = fmaf(tfi.x, fi.y, hfifv.x);           // w·F·I
                        hfifv.y = fmaf(tfi.x, V,    hfifv.y);           // w·F·V
                        const float tV = t * V;
                        hvvv.x = fmaf(t,  V, hvvv.x);                   // w·V
                        hvvv.y = fmaf(tV, V, hvvv.y);                   // w·V²
                    }
                    __builtin_amdgcn_wave_barrier();  // read->next-write

                    // vertical ring: k=0 OVERWRITES slot p, k>=1 accumulates.
                    {
                        const f32x2 w02 = (f32x2){w6[0], w6[0]};
                        acc[p][0] = w02 * hfhi;
                        acc[p][1] = w02 * hffii;
                        acc[p][2] = w02 * hfifv;
                        acc[p][3] = w02 * hvvv;
                    }
#pragma unroll
                    for (int k = 1; k < 11; ++k) {
                        const int s = (p - k + 11) % 11;   // compile-time
                        const float t = w6[k < 6 ? k : 10 - k];
                        const f32x2 t2 = (f32x2){t, t};
                        acc[s][0] = __builtin_elementwise_fma(t2, hfhi,  acc[s][0]);
                        acc[s][1] = __builtin_elementwise_fma(t2, hffii, acc[s][1]);
                        acc[s][2] = __builtin_elementwise_fma(t2, hfifv, acc[s][2]);
                        acc[s][3] = __builtin_elementwise_fma(t2, hvvv,  acc[s][3]);
                    }
                    // finalize output row r-10
                    if (r >= 10) {
                        const int s = (p + 1) % 11;        // compile-time
                        const float mu1 = acc[s][0].x, mu2 = acc[s][0].y, mu3 = acc[s][3].x;
                        const float eff = acc[s][1].x, eii = acc[s][1].y, evv = acc[s][3].y;
                        const float efi = acc[s][2].x, efv = acc[s][2].y;
                        const float mu1sq = mu1*mu1, mu2sq = mu2*mu2, mu3sq = mu3*mu3;
                        const float mu12 = mu1*mu2, mu13 = mu1*mu3;
                        const float sf  = eff - mu1sq;
                        const float si  = eii - mu2sq;
                        const float sv  = evv - mu3sq;
                        const float s12 = efi - mu12;
                        const float s13 = efv - mu13;
                        const float n1 = (2.f*mu12 + SSIM_C1) * (2.f*s12 + SSIM_C2);
                        const float d1 = (mu1sq + mu2sq + SSIM_C1) * (sf + si + SSIM_C2);
                        const float n2 = (2.f*mu13 + SSIM_C1) * (2.f*s13 + SSIM_C2);
                        const float d2 = (mu1sq + mu3sq + SSIM_C1) * (sf + sv + SSIM_C2);
                        // v_rcp_f32 (~2^-22 rel err) vs 6.6e-2 tolerance
                        const float q1 = __builtin_amdgcn_rcpf(d1);
                        const float q2 = __builtin_amdgcn_rcpf(d2);
                        if (col_ok) lssim += fmaf(n1, q1, n2 * q2);
                    }
                }
            }
        }

        // cross-wave block reduction -> one partial write (no atomic)
#pragma unroll
        for (int off = 32; off > 0; off >>= 1)
            lssim += __shfl_down(lssim, off);
        if (lane == 0) red[wv] = lssim;
        __syncthreads();
        if (tid == 0)
            ws[sidx] = red[0] + red[1] + red[2] + red[3];

    } else {
        // ================= L1+laplacian role: lidx in [0,2048) ==========
        const int lidx = g * 8 + (m - 3);
        const int yb   = lidx & 63;          // row-block 0..63 (8 rows each)
        const int b    = lidx >> 6;          // batch
        const int xq   = tid & 127;
        const int x0   = xq * 4;
        const size_t ib = (size_t)b * 512 * 512;

        const int xl = (x0 == 0)       ? 1   : x0 - 1;   // reflect (x)
        const int xr = (x0 + 4 == 512) ? 510 : x0 + 4;

        const float* Fb = fus + ib;
        const float* Ib = irp + ib;
        const float* Vb = vip + ib;

        float l1s = 0.f, grs = 0.f;

#pragma unroll
        for (int it = 0; it < 4; ++it) {
            const int y  = yb * 8 + it * 2 + (tid >> 7);
            const int ym = (y == 0)   ? 1   : y - 1;     // reflect (y)
            const int yp = (y == 511) ? 510 : y + 1;

            const float* frm = Fb + (size_t)ym*512;
            const float* frc = Fb + (size_t)y *512;
            const float* frp = Fb + (size_t)yp*512;
            const float* irm = Ib + (size_t)ym*512;
            const float* irc = Ib + (size_t)y *512;
            const float* irx = Ib + (size_t)yp*512;
            const float* vrm = Vb + (size_t)ym*512;
            const float* vrc = Vb + (size_t)y *512;
            const float* vrp = Vb + (size_t)yp*512;

            float4 fa = *(const float4*)(frm + x0);
            float4 fb4= *(const float4*)(frc + x0);
            float4 fc = *(const float4*)(frp + x0);
            float4 ia = *(const float4*)(irm + x0);
            float4 ib4= *(const float4*)(irc + x0);
            float4 ic = *(const float4*)(irx + x0);
            float4 va = *(const float4*)(vrm + x0);
            float4 vb4= *(const float4*)(vrc + x0);
            float4 vc = *(const float4*)(vrp + x0);

            const float fs0 = frm[xl]+frc[xl]+frp[xl];
            const float fs5 = frm[xr]+frc[xr]+frp[xr];
            const float is0 = irm[xl]+irc[xl]+irx[xl];
            const float is5 = irm[xr]+irc[xr]+irx[xr];
            const float vs0 = vrm[xl]+vrc[xl]+vrp[xl];
            const float vs5 = vrm[xr]+vrc[xr]+vrp[xr];

            const float fs1 = fa.x+fb4.x+fc.x, fs2 = fa.y+fb4.y+fc.y;
            const float fs3 = fa.z+fb4.z+fc.z, fs4 = fa.w+fb4.w+fc.w;
            const float is1 = ia.x+ib4.x+ic.x, is2 = ia.y+ib4.y+ic.y;
            const float is3 = ia.z+ib4.z+ic.z, is4 = ia.w+ib4.w+ic.w;
            const float vs1 = va.x+vb4.x+vc.x, vs2 = va.y+vb4.y+vc.y;
            const float vs3 = va.z+vb4.z+vc.z, vs4 = va.w+vb4.w+vc.w;

            float4 lf, li, lv;
            lf.x=(fs0+fs1+fs2-9.f*fb4.x)*0.0625f; lf.y=(fs1+fs2+fs3-9.f*fb4.y)*0.0625f;
            lf.z=(fs2+fs3+fs4-9.f*fb4.z)*0.0625f; lf.w=(fs3+fs4+fs5-9.f*fb4.w)*0.0625f;
            li.x=(is0+is1+is2-9.f*ib4.x)*0.0625f; li.y=(is1+is2+is3-9.f*ib4.y)*0.0625f;
            li.z=(is2+is3+is4-9.f*ib4.z)*0.0625f; li.w=(is3+is4+is5-9.f*ib4.w)*0.0625f;
            lv.x=(vs0+vs1+vs2-9.f*vb4.x)*0.0625f; lv.y=(vs1+vs2+vs3-9.f*vb4.y)*0.0625f;
            lv.z=(vs2+vs3+vs4-9.f*vb4.z)*0.0625f; lv.w=(vs3+vs4+vs5-9.f*vb4.w)*0.0625f;

            const float4 m1 = *(const float4*)(mir + ib + (size_t)y*512 + x0);
            const float4 m2 = *(const float4*)(mvi + ib + (size_t)y*512 + x0);

            l1s += fabsf(fmaxf(m1.x,m2.x)-fb4.x) + fabsf(fmaxf(m1.y,m2.y)-fb4.y)
                 + fabsf(fmaxf(m1.z,m2.z)-fb4.z) + fabsf(fmaxf(m1.w,m2.w)-fb4.w);

            grs += fabsf(fmaxf(fabsf(li.x),fabsf(lv.x))-fabsf(lf.x))
                 + fabsf(fmaxf(fabsf(li.y),fabsf(lv.y))-fabsf(lf.y))
                 + fabsf(fmaxf(fabsf(li.z),fabsf(lv.z))-fabsf(lf.z))
                 + fabsf(fmaxf(fabsf(li.w),fabsf(lv.w))-fabsf(lf.w));
        }

#pragma unroll
        for (int off = 32; off > 0; off >>= 1) {
            l1s += __shfl_down(l1s, off);
            grs += __shfl_down(grs, off);
        }
        if ((tid & 63) == 0) { red[tid >> 6] = l1s; red[4 + (tid >> 6)] = grs; }
        __syncthreads();
        if (tid == 0) {
            ws[768 + lidx]  = red[0] + red[1] + red[2] + red[3];
            ws[2816 + lidx] = red[4] + red[5] + red[6] + red[7];
        }
    }
}

// ---------------- final combine: reduce all partials ------------------------
__global__ void final_kernel(const float* __restrict__ ws, float* __restrict__ out)
{
    const int tid = threadIdx.x;
    float s0 = 0.f, s1 = 0.f, s2 = 0.f;
#pragma unroll
    for (int i = tid; i < 768; i += 256) s0 += ws[i];
#pragma unroll
    for (int i = tid; i < 2048; i += 256) {
        s1 += ws[768 + i];
        s2 += ws[2816 + i];
    }
#pragma unroll
    for (int off = 32; off > 0; off >>= 1) {
        s0 += __shfl_down(s0, off);
        s1 += __shfl_down(s1, off);
        s2 += __shfl_down(s2, off);
    }
    __shared__ float red[12];
    if ((tid & 63) == 0) {
        red[tid >> 6] = s0; red[4 + (tid >> 6)] = s1; red[8 + (tid >> 6)] = s2;
    }
    __syncthreads();
    if (tid == 0) {
        const float ssim_sum = red[0] + red[1] + red[2] + red[3];
        const float l1_sum   = red[4] + red[5] + red[6] + red[7];
        const float gr_sum   = red[8] + red[9] + red[10] + red[11];
        const float ms = 2.f - ssim_sum / 8064128.f;   // 32*502*502
        const float l1 = l1_sum / 8388608.f;           // 32*512*512
        const float gr = gr_sum / 8388608.f;
        out[0] = ms + l1 + 10.f * gr;
    }
}

extern "C" void kernel_launch(void* const* d_in, const int* in_sizes, int n_in,
                              void* d_out, int out_size, void* d_ws, size_t ws_size,
                              hipStream_t stream)
{
    const float* fus = (const float*)d_in[0];
    const float* irp = (const float*)d_in[1];
    const float* vip = (const float*)d_in[2];
    const float* mir = (const float*)d_in[3];
    const float* mvi = (const float*)d_in[4];
    float* out = (float*)d_out;
    float* ws  = (float*)d_ws;

    // gaussian window (matches np: f64 normalize, cast to f32)
    GaussW gw;
    double g[11], s = 0.0;
    for (int i = 0; i < 11; ++i) {
        const double d = (double)i - 5.0;
        g[i] = std::exp(-(d * d) / (2.0 * 1.5 * 1.5));
        s += g[i];
    }
    for (int i = 0; i < 11; ++i) gw.w[i] = (float)(g[i] / s);

    fused_kernel<<<2816, 256, 0, stream>>>(fus, irp, vip, mir, mvi, ws, gw);
    final_kernel<<<1, 256, 0, stream>>>(ws, out);
}

// Round 12
// 110.786 us; speedup vs baseline: 2.3347x; 1.0167x over previous
//
#include <hip/hip_runtime.h>
#include <cmath>

// FusionLoss = ms_ssim(fus,ir)+ms_ssim(fus,vi) + l1(max(map_ir,map_vi),fus)
//            + 10*mean(|max(|lap ir|,|lap vi|) - |lap fus||)
// Inputs: im_fus, im_ir, im_vi, map_ir, map_vi  each [32,1,512,512] fp32.
//
// d_ws layout (floats): [0..768)     ssim partials  (768 ssim blocks)
//                       [768..2816)  l1 partials    (2048 lapl1 blocks)
//                       [2816..4864) grad partials  (2048 lapl1 blocks)
//
// Journal: r2 atomics->partials. r5/r8/r10 spills (VGPR caps: launch_bounds
// empirically caps at 256/N: N=4->64, N=3->85). r9 best: pk-f32 pairs +
// {F,I} b64 LDS, ssim 72.9us @ VGPR 80, total 110.9us. r11 fusion NEUTRAL-NEG
// (130us fused ~= serial sum + HBM contention; VALUBusy 42%). r12 theory:
// ssim stalls on vmcnt every row (load->ds_write distance = 1 row ~400cyc <
// HBM ~600-900cyc). Fix: prefetch depth 2 via A/B register buffers +
// launch_bounds(256,2) (cap 128; 768 blocks still 3/CU resident since
// 3 x ~90 VGPR < 512/SIMD) + 22-row unroll for static buffer parity
// (22 = 2*11 keeps all ring indices compile-time).
// GUARDS: VGPR<=120, WRITE_SIZE<=50KB else spill -> revert to r9.

typedef float f32x2 __attribute__((ext_vector_type(2)));

struct GaussW { float w[11]; };

#define SSIM_C1 1.0e-4f
#define SSIM_C2 9.0e-4f

// One row step of the SSIM main loop. P is a literal 0..21 (compile-time
// after macro expansion): buffer parity, ring slots, finalize slot all fold.
#define SSIM_STEP(P, RF, RG, RV, RF2, RG2, RV2)                               \
    {                                                                         \
        const int r = rb + (P);                                               \
        if (r < in_rows) {   /* wave-uniform guard */                         \
            /* stage row r from prefetch buffer (ds_write_b64 + b32) */      \
            srow_fi[wv][lane] = (f32x2){RF, RG};                              \
            srow_v [wv][lane] = RV;                                           \
            if (extra) {                                                      \
                srow_fi[wv][64 + lane] = (f32x2){RF2, RG2};                   \
                srow_v [wv][64 + lane] = RV2;                                 \
            }                                                                 \
            __builtin_amdgcn_wave_barrier();  /* write->read order */         \
            /* depth-2 prefetch: row r+2 into the SAME buffer (freed by the  \
               ds_write above); consumed 2 rows (~750cyc) later */            \
            if (r + 2 < in_rows) {                                            \
                const size_t base = (size_t)(r0 + r + 2) * 512 + col;         \
                RF = Fp[base]; RG = Ip[base]; RV = Vp[base];                  \
                if (extra_ok) {                                               \
                    const size_t b2 = (size_t)(r0 + r + 2) * 512 + col2;      \
                    RF2 = Fp[b2]; RG2 = Ip[b2]; RV2 = Vp[b2];                 \
                }                                                             \
            }                                                                 \
            /* horizontal gaussian sums, packed-f32 where pairable */         \
            f32x2 hfhi  = (f32x2)(0.f);   /* {Sw*F,  Sw*I}  */                \
            f32x2 hffii = (f32x2)(0.f);   /* {Sw*F2, Sw*I2} */                \
            f32x2 hfifv = (f32x2)(0.f);   /* {Sw*FI, Sw*FV} */                \
            f32x2 hvvv  = (f32x2)(0.f);   /* {Sw*V,  Sw*V2} */                \
            _Pragma("unroll")                                                 \
            for (int k = 0; k < 11; ++k) {                                    \
                const float t = w6[k < 6 ? k : 10 - k];                       \
                const f32x2 fi = srow_fi[wv][lane + k];                       \
                const float V  = srow_v [wv][lane + k];                       \
                const f32x2 t2 = (f32x2){t, t};                               \
                const f32x2 tfi = t2 * fi;                                    \
                hfhi  = __builtin_elementwise_fma(t2,  fi, hfhi);             \
                hffii = __builtin_elementwise_fma(tfi, fi, hffii);            \
                hfifv.x = fmaf(tfi.x, fi.y, hfifv.x);                         \
                hfifv.y = fmaf(tfi.x, V,    hfifv.y);                         \
                const float tV = t * V;                                       \
                hvvv.x = fmaf(t,  V, hvvv.x);                                 \
                hvvv.y = fmaf(tV, V, hvvv.y);                                 \
            }                                                                 \
            __builtin_amdgcn_wave_barrier();  /* read->next-write */          \
            /* vertical ring: k=0 OVERWRITES slot P%11 (wipes phantom),      \
               k>=1 accumulates. All slot indices compile-time. */            \
            {                                                                 \
                const f32x2 w02 = (f32x2){w6[0], w6[0]};                      \
                acc[(P) % 11][0] = w02 * hfhi;                                \
                acc[(P) % 11][1] = w02 * hffii;                               \
                acc[(P) % 11][2] = w02 * hfifv;                               \
                acc[(P) % 11][3] = w02 * hvvv;                                \
            }                                                                 \
            _Pragma("unroll")                                                 \
            for (int k = 1; k < 11; ++k) {                                    \
                const int s = ((P) - k + 22) % 11;                            \
                const float t = w6[k < 6 ? k : 10 - k];                       \
                const f32x2 t2 = (f32x2){t, t};                               \
                acc[s][0] = __builtin_elementwise_fma(t2, hfhi,  acc[s][0]);  \
                acc[s][1] = __builtin_elementwise_fma(t2, hffii, acc[s][1]);  \
                acc[s][2] = __builtin_elementwise_fma(t2, hfifv, acc[s][2]);  \
                acc[s][3] = __builtin_elementwise_fma(t2, hvvv,  acc[s][3]);  \
            }                                                                 \
            /* finalize output row r-10 (slot just got its k=10 term) */      \
            if (r >= 10) {                                                    \
                const int s = ((P) + 1) % 11;                                 \
                const float mu1 = acc[s][0].x, mu2 = acc[s][0].y;             \
                const float mu3 = acc[s][3].x;                                \
                const float eff = acc[s][1].x, eii = acc[s][1].y;             \
                const float evv = acc[s][3].y;                                \
                const float efi = acc[s][2].x, efv = acc[s][2].y;             \
                const float mu1sq = mu1*mu1, mu2sq = mu2*mu2, mu3sq = mu3*mu3;\
                const float mu12 = mu1*mu2, mu13 = mu1*mu3;                   \
                const float sf  = eff - mu1sq;                                \
                const float si  = eii - mu2sq;                                \
                const float sv  = evv - mu3sq;                                \
                const float s12 = efi - mu12;                                 \
                const float s13 = efv - mu13;                                 \
                const float n1 = (2.f*mu12 + SSIM_C1) * (2.f*s12 + SSIM_C2);  \
                const float d1 = (mu1sq + mu2sq + SSIM_C1) * (sf + si + SSIM_C2); \
                const float n2 = (2.f*mu13 + SSIM_C1) * (2.f*s13 + SSIM_C2);  \
                const float d2 = (mu1sq + mu3sq + SSIM_C1) * (sf + sv + SSIM_C2); \
                const float q1 = __builtin_amdgcn_rcpf(d1);                   \
                const float q2 = __builtin_amdgcn_rcpf(d2);                   \
                if (col_ok) lssim += fmaf(n1, q1, n2 * q2);                   \
            }                                                                 \
        }                                                                     \
    }

// ---------------- Kernel A: fused double SSIM (separable 11x11 gaussian) ----
// Grid: (2 col blocks of 256, 12 row strips of 42, 32 batch) = 768 blocks
// = 3 blocks/CU resident (VGPR ~90 -> 5 waves/SIMD possible, grid-limited).
// Block = 4 independent waves; wave wv owns 64 cols; wave-private LDS rows.
// No __syncthreads in the main loop (in-order DS pipe within a wave;
// wave_barrier() fences compiler reordering, zero-cost).
__global__ __launch_bounds__(256, 2)
void ssim_kernel(const float* __restrict__ fus, const float* __restrict__ irp,
                 const float* __restrict__ vip, float* __restrict__ part,
                 GaussW gw)
{
    const int b    = blockIdx.z;
    const int r0   = blockIdx.y * 42;
    const int tid  = threadIdx.x;
    const int wv   = tid >> 6;          // wave 0..3
    const int lane = tid & 63;
    const int c0   = blockIdx.x * 256 + wv * 64;   // wave's column base
    const int out_rows = min(42, 502 - r0);        // last strip: 40
    const int in_rows  = out_rows + 10;            // 50..52

    const size_t ib = (size_t)b * 512 * 512;
    const float* __restrict__ Fp = fus + ib;
    const float* __restrict__ Ip = irp + ib;
    const float* __restrict__ Vp = vip + ib;

    __shared__ f32x2 srow_fi[4][80];    // wave-private {F,I} pairs
    __shared__ float srow_v [4][80];    // wave-private V

    float w6[6];                        // gaussian symmetric: w[k]=w[10-k]
#pragma unroll
    for (int k = 0; k < 6; ++k) w6[k] = gw.w[k];

    // register ring: 11 rows x 4 f32x2 pairs:
    //   [0]={hf,hi} [1]={hff,hii} [2]={hfi,hfv} [3]={hv,hvv}
    f32x2 acc[11][4];
#pragma unroll
    for (int s = 0; s < 11; ++s)
#pragma unroll
        for (int q = 0; q < 4; ++q) acc[s][q] = (f32x2)(0.f);

    float lssim = 0.f;
    const int  col      = c0 + lane;
    const bool col_ok   = col <= 501;             // valid output column
    const bool extra    = lane < 10;              // loads the 10-col halo
    const int  col2     = c0 + 64 + lane;
    const bool extra_ok = extra && (col2 < 512);

    // prologue: prefetch rows 0 and 1 into buffers A and B (in_rows >= 50)
    float arf, arg, arv, arf2 = 0.f, arg2 = 0.f, arv2 = 0.f;
    float brf, brg, brv, brf2 = 0.f, brg2 = 0.f, brv2 = 0.f;
    {
        const size_t b0 = (size_t)r0 * 512 + col;
        arf = Fp[b0]; arg = Ip[b0]; arv = Vp[b0];
        const size_t b1 = (size_t)(r0 + 1) * 512 + col;
        brf = Fp[b1]; brg = Ip[b1]; brv = Vp[b1];
        if (extra_ok) {
            const size_t c20 = (size_t)r0 * 512 + col2;
            arf2 = Fp[c20]; arg2 = Ip[c20]; arv2 = Vp[c20];
            const size_t c21 = (size_t)(r0 + 1) * 512 + col2;
            brf2 = Fp[c21]; brg2 = Ip[c21]; brv2 = Vp[c21];
        }
    }

#pragma unroll 1
    for (int rb = 0; rb < 66; rb += 22) {
        SSIM_STEP(0,  arf, arg, arv, arf2, arg2, arv2)
        SSIM_STEP(1,  brf, brg, brv, brf2, brg2, brv2)
        SSIM_STEP(2,  arf, arg, arv, arf2, arg2, arv2)
        SSIM_STEP(3,  brf, brg, brv, brf2, brg2, brv2)
        SSIM_STEP(4,  arf, arg, arv, arf2, arg2, arv2)
        SSIM_STEP(5,  brf, brg, brv, brf2, brg2, brv2)
        SSIM_STEP(6,  arf, arg, arv, arf2, arg2, arv2)
        SSIM_STEP(7,  brf, brg, brv, brf2, brg2, brv2)
        SSIM_STEP(8,  arf, arg, arv, arf2, arg2, arv2)
        SSIM_STEP(9,  brf, brg, brv, brf2, brg2, brv2)
        SSIM_STEP(10, arf, arg, arv, arf2, arg2, arv2)
        SSIM_STEP(11, brf, brg, brv, brf2, brg2, brv2)
        SSIM_STEP(12, arf, arg, arv, arf2, arg2, arv2)
        SSIM_STEP(13, brf, brg, brv, brf2, brg2, brv2)
        SSIM_STEP(14, arf, arg, arv, arf2, arg2, arv2)
        SSIM_STEP(15, brf, brg, brv, brf2, brg2, brv2)
        SSIM_STEP(16, arf, arg, arv, arf2, arg2, arv2)
        SSIM_STEP(17, brf, brg, brv, brf2, brg2, brv2)
        SSIM_STEP(18, arf, arg, arv, arf2, arg2, arv2)
        SSIM_STEP(19, brf, brg, brv, brf2, brg2, brv2)
        SSIM_STEP(20, arf, arg, arv, arf2, arg2, arv2)
        SSIM_STEP(21, brf, brg, brv, brf2, brg2, brv2)
    }

    // cross-wave block reduction -> one partial write (no atomic)
#pragma unroll
    for (int off = 32; off > 0; off >>= 1)
        lssim += __shfl_down(lssim, off);
    __shared__ float red[4];
    if (lane == 0) red[wv] = lssim;
    __syncthreads();
    if (tid == 0) {
        const int blk = blockIdx.x + 2 * (blockIdx.y + 12 * blockIdx.z); // 0..767
        part[blk] = red[0] + red[1] + red[2] + red[3];
    }
}

// ---------------- Kernel B: L1 + laplacian grad loss ------------------------
__device__ inline float4 lap3x3(const float* __restrict__ rm,
                                const float* __restrict__ rc,
                                const float* __restrict__ rp,
                                int x0, int xl, int xr, float4& center)
{
    float4 a = *(const float4*)(rm + x0);
    float4 b = *(const float4*)(rc + x0);
    float4 c = *(const float4*)(rp + x0);
    const float aL = rm[xl], bL = rc[xl], cL = rp[xl];
    const float aR = rm[xr], bR = rc[xr], cR = rp[xr];
    const float s0 = aL + bL + cL;
    const float s1 = a.x + b.x + c.x;
    const float s2 = a.y + b.y + c.y;
    const float s3 = a.z + b.z + c.z;
    const float s4 = a.w + b.w + c.w;
    const float s5 = aR + bR + cR;
    center = b;
    float4 l;
    l.x = (s0 + s1 + s2 - 9.f*b.x) * 0.0625f;
    l.y = (s1 + s2 + s3 - 9.f*b.y) * 0.0625f;
    l.z = (s2 + s3 + s4 - 9.f*b.z) * 0.0625f;
    l.w = (s3 + s4 + s5 - 9.f*b.w) * 0.0625f;
    return l;
}

// Grid: dim3(64, 32) = 2048 blocks; each block covers 8 rows of one batch
// image (4 iterations x 2 rows). Partial sums to d_ws, no atomics.
__global__ __launch_bounds__(256, 4)
void lapl1_kernel(const float* __restrict__ fus, const float* __restrict__ irp,
                  const float* __restrict__ vip, const float* __restrict__ mir,
                  const float* __restrict__ mvi,
                  float* __restrict__ part_l1, float* __restrict__ part_gr)
{
    const int b   = blockIdx.y;
    const int tid = threadIdx.x;
    const int xq  = tid & 127;
    const int x0  = xq * 4;
    const size_t ib = (size_t)b * 512 * 512;

    const int xl = (x0 == 0)        ? 1   : x0 - 1;   // reflect padding (x)
    const int xr = (x0 + 4 == 512)  ? 510 : x0 + 4;

    const float* Fb = fus + ib;
    const float* Ib = irp + ib;
    const float* Vb = vip + ib;

    float l1s = 0.f, grs = 0.f;

#pragma unroll
    for (int it = 0; it < 4; ++it) {
        const int y  = blockIdx.x * 8 + it * 2 + (tid >> 7);
        const int ym = (y == 0)   ? 1   : y - 1;       // reflect padding (y)
        const int yp = (y == 511) ? 510 : y + 1;

        float4 cf, ci, cv;
        const float4 lf = lap3x3(Fb + (size_t)ym*512, Fb + (size_t)y*512, Fb + (size_t)yp*512, x0, xl, xr, cf);
        const float4 li = lap3x3(Ib + (size_t)ym*512, Ib + (size_t)y*512, Ib + (size_t)yp*512, x0, xl, xr, ci);
        const float4 lv = lap3x3(Vb + (size_t)ym*512, Vb + (size_t)y*512, Vb + (size_t)yp*512, x0, xl, xr, cv);

        const float4 m1 = *(const float4*)(mir + ib + (size_t)y*512 + x0);
        const float4 m2 = *(const float4*)(mvi + ib + (size_t)y*512 + x0);

        l1s += fabsf(fmaxf(m1.x, m2.x) - cf.x) + fabsf(fmaxf(m1.y, m2.y) - cf.y)
             + fabsf(fmaxf(m1.z, m2.z) - cf.z) + fabsf(fmaxf(m1.w, m2.w) - cf.w);

        grs += fabsf(fmaxf(fabsf(li.x), fabsf(lv.x)) - fabsf(lf.x))
             + fabsf(fmaxf(fabsf(li.y), fabsf(lv.y)) - fabsf(lf.y))
             + fabsf(fmaxf(fabsf(li.z), fabsf(lv.z)) - fabsf(lf.z))
             + fabsf(fmaxf(fabsf(li.w), fabsf(lv.w)) - fabsf(lf.w));
    }

#pragma unroll
    for (int off = 32; off > 0; off >>= 1) {
        l1s += __shfl_down(l1s, off);
        grs += __shfl_down(grs, off);
    }
    __shared__ float red[8];
    if ((tid & 63) == 0) { red[tid >> 6] = l1s; red[4 + (tid >> 6)] = grs; }
    __syncthreads();
    if (tid == 0) {
        const int blk = blockIdx.x + 64 * blockIdx.y;  // 0..2047
        part_l1[blk] = red[0] + red[1] + red[2] + red[3];
        part_gr[blk] = red[4] + red[5] + red[6] + red[7];
    }
}

// ---------------- final combine: reduce all partials ------------------------
__global__ void final_kernel(const float* __restrict__ ws, float* __restrict__ out)
{
    const int tid = threadIdx.x;
    float s0 = 0.f, s1 = 0.f, s2 = 0.f;
#pragma unroll
    for (int i = tid; i < 768; i += 256) s0 += ws[i];
#pragma unroll
    for (int i = tid; i < 2048; i += 256) {
        s1 += ws[768 + i];
        s2 += ws[2816 + i];
    }
#pragma unroll
    for (int off = 32; off > 0; off >>= 1) {
        s0 += __shfl_down(s0, off);
        s1 += __shfl_down(s1, off);
        s2 += __shfl_down(s2, off);
    }
    __shared__ float red[12];
    if ((tid & 63) == 0) {
        red[tid >> 6] = s0; red[4 + (tid >> 6)] = s1; red[8 + (tid >> 6)] = s2;
    }
    __syncthreads();
    if (tid == 0) {
        const float ssim_sum = red[0] + red[1] + red[2] + red[3];
        const float l1_sum   = red[4] + red[5] + red[6] + red[7];
        const float gr_sum   = red[8] + red[9] + red[10] + red[11];
        const float ms = 2.f - ssim_sum / 8064128.f;   // 32*502*502
        const float l1 = l1_sum / 8388608.f;           // 32*512*512
        const float gr = gr_sum / 8388608.f;
        out[0] = ms + l1 + 10.f * gr;
    }
}

extern "C" void kernel_launch(void* const* d_in, const int* in_sizes, int n_in,
                              void* d_out, int out_size, void* d_ws, size_t ws_size,
                              hipStream_t stream)
{
    const float* fus = (const float*)d_in[0];
    const float* irp = (const float*)d_in[1];
    const float* vip = (const float*)d_in[2];
    const float* mir = (const float*)d_in[3];
    const float* mvi = (const float*)d_in[4];
    float* out = (float*)d_out;
    float* ws  = (float*)d_ws;

    // gaussian window (matches np: f64 normalize, cast to f32)
    GaussW gw;
    double g[11], s = 0.0;
    for (int i = 0; i < 11; ++i) {
        const double d = (double)i - 5.0;
        g[i] = std::exp(-(d * d) / (2.0 * 1.5 * 1.5));
        s += g[i];
    }
    for (int i = 0; i < 11; ++i) gw.w[i] = (float)(g[i] / s);

    ssim_kernel<<<dim3(2, 12, 32), 256, 0, stream>>>(fus, irp, vip, ws, gw);
    lapl1_kernel<<<dim3(64, 32), 256, 0, stream>>>(fus, irp, vip, mir, mvi,
                                                   ws + 768, ws + 2816);
    final_kernel<<<1, 256, 0, stream>>>(ws, out);
}